// Round 1
// baseline (418.906 us; speedup 1.0000x reference)
//
#include <hip/hip_runtime.h>

#define NF 16
#define HIDN 32
#define NB 32
#define NN 64
#define EPSV 1e-8f

// Workspace layout (float offsets):
//   s     : 0       (NB*NN*16 = 32768)
//   vec   : 32768   (NB*NN*48 = 98304)
//   agg_s : 131072  (32768)
//   agg_v : 163840  (98304)
//   A     : 262144  (NB*NN*4224 = 8650752)   total ~35.7 MB
// Per-node A block (4224 floats = 16 chunks * 256 + 128 bias):
//   lane lz = hq*16+i  (hq = h-quarter 0..3, i = output row 0..15)
//   chunk c, lane lz, comp t  ->  float offset c*256 + lz*4 + t
//   c0,c1   : A_ss[i][h]  h = hq*8 + c*4 + t
//   c2,c3   : A_sv[i][h]
//   c4..c9  : A_vs[i][h][d]  f=(c-4)*4+t = (h%8)*3+d
//   c10..c15: A_vv[i][h][d]
//   bias at 4096 + i*8: [Ab_ss, Ab_sv, Ab_vs[3], Ab_vv[3]]

__global__ void k_init(const float* __restrict__ z, const float* __restrict__ v,
                       const float* __restrict__ w_s_in, const float* __restrict__ w_v_in,
                       float* __restrict__ s, float* __restrict__ vec) {
    int idx = blockIdx.x * blockDim.x + threadIdx.x;
    if (idx < NB * NN * 16) {
        s[idx] = z[idx >> 4] * w_s_in[idx & 15];
    } else {
        int i2 = idx - NB * NN * 16;
        if (i2 < NB * NN * 48) {
            int node = i2 / 48, rem = i2 % 48;
            int ch = rem / 3, d = rem % 3;
            vec[i2] = v[node * 3 + d] * w_v_in[ch];
        }
    }
}

__global__ __launch_bounds__(512) void k_precompute(
        const float* __restrict__ s, const float* __restrict__ vec,
        const float* __restrict__ W2, const float* __restrict__ b2,
        float* __restrict__ A) {
    int node = blockIdx.x;
    int tid = threadIdx.x;
    int i = tid & 15, h = tid >> 4;          // i in [0,16), h in [0,32)
    __shared__ float s_sh[16];
    __shared__ float vec_sh[48];
    if (tid < 16) s_sh[tid] = s[node * 16 + tid];
    else if (tid < 64) vec_sh[tid - 16] = vec[node * 48 + (tid - 16)];
    __syncthreads();

    float* Anode = A + (size_t)node * 4224;
    const float* wss = W2 + h * 1024 + i * 16;
    const float* wsv = wss + 256;
    const float* wvs = wss + 512;
    const float* wvv = wss + 768;

    float a_ss = 0.f, a_sv = 0.f;
    float avs[3] = {0.f, 0.f, 0.f};
    float avv[3] = {0.f, 0.f, 0.f};
#pragma unroll
    for (int j = 0; j < 16; ++j) {
        float sj = s_sh[j];
        float v0 = vec_sh[j * 3 + 0], v1 = vec_sh[j * 3 + 1], v2 = vec_sh[j * 3 + 2];
        a_ss += wss[j] * sj;
        a_sv += wsv[j] * sj;
        float wa = wvs[j];
        avs[0] += wa * v0; avs[1] += wa * v1; avs[2] += wa * v2;
        float wb = wvv[j];
        avv[0] += wb * v0; avv[1] += wb * v1; avv[2] += wb * v2;
    }
    int hq = h >> 3, t8 = h & 7;
    int lz = hq * 16 + i;
    Anode[(t8 >> 2) * 256 + lz * 4 + (t8 & 3)] = a_ss;
    Anode[(2 + (t8 >> 2)) * 256 + lz * 4 + (t8 & 3)] = a_sv;
#pragma unroll
    for (int d = 0; d < 3; ++d) {
        int f = t8 * 3 + d;
        Anode[(4 + (f >> 2)) * 256 + lz * 4 + (f & 3)] = avs[d];
        Anode[(10 + (f >> 2)) * 256 + lz * 4 + (f & 3)] = avv[d];
    }
    if (h == 0) {
        float b_ss = 0.f, b_sv = 0.f;
        float bvs[3] = {0.f, 0.f, 0.f};
        float bvv[3] = {0.f, 0.f, 0.f};
#pragma unroll
        for (int j = 0; j < 16; ++j) {
            float sj = s_sh[j];
            float v0 = vec_sh[j * 3 + 0], v1 = vec_sh[j * 3 + 1], v2 = vec_sh[j * 3 + 2];
            b_ss += b2[i * 16 + j] * sj;
            b_sv += b2[256 + i * 16 + j] * sj;
            float ba = b2[512 + i * 16 + j];
            bvs[0] += ba * v0; bvs[1] += ba * v1; bvs[2] += ba * v2;
            float bb = b2[768 + i * 16 + j];
            bvv[0] += bb * v0; bvv[1] += bb * v1; bvv[2] += bb * v2;
        }
        float* Bp = Anode + 4096 + i * 8;
        Bp[0] = b_ss; Bp[1] = b_sv;
        Bp[2] = bvs[0]; Bp[3] = bvs[1]; Bp[4] = bvs[2];
        Bp[5] = bvv[0]; Bp[6] = bvv[1]; Bp[7] = bvv[2];
    }
}

__global__ __launch_bounds__(256) void k_edge(
        const float* __restrict__ pos,
        const float* __restrict__ A,
        const float* __restrict__ w1, const float* __restrict__ b1,
        float* __restrict__ agg_s, float* __restrict__ agg_v) {
    // XCD-aware swizzle: batch b -> xcd b/4, so a batch's A block (~1MB) stays in one L2
    int blk = blockIdx.x;              // 0..511
    int xcd = blk & 7;
    int k = blk >> 3;                  // 0..63
    int b = xcd * 4 + (k >> 4);
    int dgrp = k & 15;
    int w = threadIdx.x >> 6;          // wave id 0..3
    int lane = threadIdx.x & 63;
    int dst = dgrp * 4 + w;
    int i = lane & 15, hq = lane >> 4;

    __shared__ float pos_sh[NN * 3];
    if (threadIdx.x < NN * 3) pos_sh[threadIdx.x] = pos[(size_t)b * NN * 3 + threadIdx.x];
    __syncthreads();

    float pdx = pos_sh[dst * 3 + 0], pdy = pos_sh[dst * 3 + 1], pdz = pos_sh[dst * 3 + 2];
    float w1r[8], b1r[8];
#pragma unroll
    for (int t = 0; t < 8; ++t) {
        w1r[t] = w1[hq * 8 + t];
        b1r[t] = b1[hq * 8 + t];
    }

    float acc_ms = 0.f, acc_mv0 = 0.f, acc_mv1 = 0.f, acc_mv2 = 0.f;
    const float4* Abase = (const float4*)(A + (size_t)b * NN * 4224);

    for (int grp = 0; grp < 8; ++grp) {
        __syncthreads();   // keep the 4 waves on the same A[src] window for L1 reuse
        for (int t0 = 0; t0 < 8; ++t0) {
            int src = grp * 8 + t0;
            if (src == dst) continue;
            const float4* Af = Abase + (size_t)src * 1056;
            float4 as0 = Af[0 * 64 + lane];
            float4 as1 = Af[1 * 64 + lane];
            float4 ax0 = Af[2 * 64 + lane];
            float4 ax1 = Af[3 * 64 + lane];
            float avsA[24], avvA[24];
#pragma unroll
            for (int q = 0; q < 6; ++q) {
                float4 tv = Af[(4 + q) * 64 + lane];
                avsA[q * 4 + 0] = tv.x; avsA[q * 4 + 1] = tv.y;
                avsA[q * 4 + 2] = tv.z; avsA[q * 4 + 3] = tv.w;
            }
#pragma unroll
            for (int q = 0; q < 6; ++q) {
                float4 tv = Af[(10 + q) * 64 + lane];
                avvA[q * 4 + 0] = tv.x; avvA[q * 4 + 1] = tv.y;
                avvA[q * 4 + 2] = tv.z; avvA[q * 4 + 3] = tv.w;
            }
            float asl[8]  = {as0.x, as0.y, as0.z, as0.w, as1.x, as1.y, as1.z, as1.w};
            float asvl[8] = {ax0.x, ax0.y, ax0.z, ax0.w, ax1.x, ax1.y, ax1.z, ax1.w};

            float dx = pdx - pos_sh[src * 3 + 0];
            float dy = pdy - pos_sh[src * 3 + 1];
            float dz = pdz - pos_sh[src * 3 + 2];
            float r = sqrtf(dx * dx + dy * dy + dz * dz);
            float inv = 1.f / (r + EPSV);
            float ux = dx * inv, uy = dy * inv, uz = dz * inv;

            float ms = 0.f, tt = 0.f, mv0 = 0.f, mv1 = 0.f, mv2 = 0.f;
#pragma unroll
            for (int hh = 0; hh < 8; ++hh) {
                float hv = r * w1r[hh] + b1r[hh];
                hv = hv > 0.f ? hv : 0.f;
                ms += hv * asl[hh];
                tt += hv * asvl[hh];
                ms += hv * (ux * avsA[hh * 3 + 0] + uy * avsA[hh * 3 + 1] + uz * avsA[hh * 3 + 2]);
                mv0 += hv * avvA[hh * 3 + 0];
                mv1 += hv * avvA[hh * 3 + 1];
                mv2 += hv * avvA[hh * 3 + 2];
            }
            if (hq == 0) {
                const float* Bp = (const float*)Af + 4096 + i * 8;
                ms += Bp[0] + ux * Bp[2] + uy * Bp[3] + uz * Bp[4];
                tt += Bp[1];
                mv0 += Bp[5]; mv1 += Bp[6]; mv2 += Bp[7];
            }
            mv0 += tt * ux; mv1 += tt * uy; mv2 += tt * uz;
            acc_ms += ms; acc_mv0 += mv0; acc_mv1 += mv1; acc_mv2 += mv2;
        }
    }

    acc_ms  += __shfl_xor(acc_ms, 16, 64);  acc_ms  += __shfl_xor(acc_ms, 32, 64);
    acc_mv0 += __shfl_xor(acc_mv0, 16, 64); acc_mv0 += __shfl_xor(acc_mv0, 32, 64);
    acc_mv1 += __shfl_xor(acc_mv1, 16, 64); acc_mv1 += __shfl_xor(acc_mv1, 32, 64);
    acc_mv2 += __shfl_xor(acc_mv2, 16, 64); acc_mv2 += __shfl_xor(acc_mv2, 32, 64);

    if (hq == 0) {
        int node = b * NN + dst;
        agg_s[node * 16 + i] = acc_ms;
        agg_v[node * 48 + i * 3 + 0] = acc_mv0;
        agg_v[node * 48 + i * 3 + 1] = acc_mv1;
        agg_v[node * 48 + i * 3 + 2] = acc_mv2;
    }
}

__global__ __launch_bounds__(64) void k_node(
        const float* __restrict__ agg_s, const float* __restrict__ agg_v,
        const float* __restrict__ ws, const float* __restrict__ wv,
        float* __restrict__ s, float* __restrict__ vec) {
    int node = blockIdx.x;
    int tid = threadIdx.x;
    __shared__ float ash[16];
    __shared__ float avh[48];
    if (tid < 16) ash[tid] = agg_s[node * 16 + tid];
    else if (tid < 64) avh[tid - 16] = agg_v[node * 48 + tid - 16];
    __syncthreads();
    int e = tid & 15, p = tid >> 4;
    if (p == 0) {
        float acc = 0.f;
#pragma unroll
        for (int c = 0; c < 16; ++c) acc += ash[c] * ws[c * 16 + e];
        s[node * 16 + e] += fmaxf(acc, 0.f);
    } else {
        int d = p - 1;
        float acc = 0.f;
#pragma unroll
        for (int c = 0; c < 16; ++c) acc += avh[c * 3 + d] * wv[c * 16 + e];
        vec[node * 48 + e * 3 + d] += acc;
    }
}

__global__ void k_out(const float* __restrict__ vec, const float* __restrict__ wvo,
                      const float* __restrict__ pos, float* __restrict__ out) {
    int idx = blockIdx.x * blockDim.x + threadIdx.x;
    if (idx >= NB * NN * 3) return;
    int node = idx / 3, d = idx % 3;
    float acc = 0.f;
#pragma unroll
    for (int c = 0; c < 16; ++c) acc += vec[node * 48 + c * 3 + d] * wvo[c];
    out[idx] = acc + pos[idx];
}

extern "C" void kernel_launch(void* const* d_in, const int* in_sizes, int n_in,
                              void* d_out, int out_size, void* d_ws, size_t ws_size,
                              hipStream_t stream) {
    const float* pos = (const float*)d_in[0];
    const float* v   = (const float*)d_in[1];
    const float* z   = (const float*)d_in[2];
    const float* w_s_in = (const float*)d_in[3];
    const float* w_v_in = (const float*)d_in[4];
    const float* rw1 = (const float*)d_in[5];
    const float* rb1 = (const float*)d_in[6];
    const float* rw2 = (const float*)d_in[7];
    const float* rb2 = (const float*)d_in[8];
    const float* sws = (const float*)d_in[9];
    const float* swv = (const float*)d_in[10];
    const float* wvo = (const float*)d_in[11];
    float* out = (float*)d_out;

    float* wsf  = (float*)d_ws;
    float* s    = wsf;
    float* vec  = wsf + 32768;
    float* aggs = wsf + 131072;
    float* aggv = wsf + 163840;
    float* A    = wsf + 262144;

    k_init<<<512, 256, 0, stream>>>(z, v, w_s_in, w_v_in, s, vec);
    for (int l = 0; l < 3; ++l) {
        k_precompute<<<NB * NN, 512, 0, stream>>>(s, vec, rw2 + l * HIDN * 1024,
                                                  rb2 + l * 1024, A);
        k_edge<<<512, 256, 0, stream>>>(pos, A, rw1 + l * HIDN, rb1 + l * HIDN,
                                        aggs, aggv);
        k_node<<<NB * NN, 64, 0, stream>>>(aggs, aggv, sws + l * 256, swv + l * 256,
                                           s, vec);
    }
    k_out<<<24, 256, 0, stream>>>(vec, wvo, pos, out);
}

// Round 2
// 277.300 us; speedup vs baseline: 1.5107x; 1.5107x over previous
//
#include <hip/hip_runtime.h>

#define NF 16
#define HIDN 32
#define NB 32
#define NN 64
#define EPSV 1e-8f

// Workspace layout (float offsets):
//   s    : 0        (32768)
//   vec  : 32768    (98304)
//   aggs : 131072   (8 * 32768  = 262144)   per-srcgrp partials
//   aggv : 393216   (8 * 98304  = 786432)
//   A    : 1179648  (NB*NN*4224 = 8650752)  total ~39.3 MB
// Per-node A block (4224 floats = 16 chunks * 256 + 128 bias):
//   lane lz = hq*16+i ; chunk c, comp t -> float offset c*256 + lz*4 + t
//   c0,c1: A_ss[i][h]  (h = hq*8 + c*4 + t)
//   c2,c3: A_sv[i][h]
//   c4..c9:  A_vs[i][h][d]  f=(c-4)*4+t = (h%8)*3+d
//   c10..c15:A_vv[i][h][d]
//   bias at 4096 + i*8: [b_ss, b_sv, bvs0..2, bvv0..2]

#define S_OFF    0
#define VEC_OFF  32768
#define AGGS_OFF 131072
#define AGGV_OFF 393216
#define A_OFF    1179648

__device__ __forceinline__ void pre_phase2(
        int node0, int tid,
        const float (*s_sh)[16], const float (*vec_sh)[48],
        const float* __restrict__ W2, const float* __restrict__ b2,
        float* __restrict__ A) {
    int i = tid & 15, h = tid >> 4;          // i in [0,16), h in [0,32)
    const float* wbase = W2 + h * 1024 + i * 16;
    float wr[4][16];
#pragma unroll
    for (int q = 0; q < 4; ++q) {
        const float4* p = (const float4*)(wbase + q * 256);
        float4 x0 = p[0], x1 = p[1], x2 = p[2], x3 = p[3];
        wr[q][0] = x0.x; wr[q][1] = x0.y; wr[q][2] = x0.z; wr[q][3] = x0.w;
        wr[q][4] = x1.x; wr[q][5] = x1.y; wr[q][6] = x1.z; wr[q][7] = x1.w;
        wr[q][8] = x2.x; wr[q][9] = x2.y; wr[q][10] = x2.z; wr[q][11] = x2.w;
        wr[q][12] = x3.x; wr[q][13] = x3.y; wr[q][14] = x3.z; wr[q][15] = x3.w;
    }
    int hq = h >> 3, t8 = h & 7, lz = hq * 16 + i;
#pragma unroll
    for (int k = 0; k < 4; ++k) {
        float a_ss = 0.f, a_sv = 0.f;
        float avs[3] = {0.f, 0.f, 0.f};
        float avv[3] = {0.f, 0.f, 0.f};
#pragma unroll
        for (int j = 0; j < 16; ++j) {
            float sj = s_sh[k][j];
            float v0 = vec_sh[k][j * 3 + 0], v1 = vec_sh[k][j * 3 + 1], v2 = vec_sh[k][j * 3 + 2];
            a_ss += wr[0][j] * sj;
            a_sv += wr[1][j] * sj;
            float wa = wr[2][j];
            avs[0] += wa * v0; avs[1] += wa * v1; avs[2] += wa * v2;
            float wb = wr[3][j];
            avv[0] += wb * v0; avv[1] += wb * v1; avv[2] += wb * v2;
        }
        float* Anode = A + (size_t)(node0 + k) * 4224;
        Anode[(t8 >> 2) * 256 + lz * 4 + (t8 & 3)] = a_ss;
        Anode[(2 + (t8 >> 2)) * 256 + lz * 4 + (t8 & 3)] = a_sv;
#pragma unroll
        for (int d = 0; d < 3; ++d) {
            int f = t8 * 3 + d;
            Anode[(4 + (f >> 2)) * 256 + lz * 4 + (f & 3)] = avs[d];
            Anode[(10 + (f >> 2)) * 256 + lz * 4 + (f & 3)] = avv[d];
        }
    }
    if (h == 0) {
        float br[4][16];
#pragma unroll
        for (int q = 0; q < 4; ++q) {
            const float4* p = (const float4*)(b2 + q * 256 + i * 16);
            float4 x0 = p[0], x1 = p[1], x2 = p[2], x3 = p[3];
            br[q][0] = x0.x; br[q][1] = x0.y; br[q][2] = x0.z; br[q][3] = x0.w;
            br[q][4] = x1.x; br[q][5] = x1.y; br[q][6] = x1.z; br[q][7] = x1.w;
            br[q][8] = x2.x; br[q][9] = x2.y; br[q][10] = x2.z; br[q][11] = x2.w;
            br[q][12] = x3.x; br[q][13] = x3.y; br[q][14] = x3.z; br[q][15] = x3.w;
        }
#pragma unroll
        for (int k = 0; k < 4; ++k) {
            float b_ss = 0.f, b_sv = 0.f;
            float bvs[3] = {0.f, 0.f, 0.f};
            float bvv[3] = {0.f, 0.f, 0.f};
#pragma unroll
            for (int j = 0; j < 16; ++j) {
                float sj = s_sh[k][j];
                float v0 = vec_sh[k][j * 3 + 0], v1 = vec_sh[k][j * 3 + 1], v2 = vec_sh[k][j * 3 + 2];
                b_ss += br[0][j] * sj;
                b_sv += br[1][j] * sj;
                float ba = br[2][j];
                bvs[0] += ba * v0; bvs[1] += ba * v1; bvs[2] += ba * v2;
                float bb = br[3][j];
                bvv[0] += bb * v0; bvv[1] += bb * v1; bvv[2] += bb * v2;
            }
            float* Bp = A + (size_t)(node0 + k) * 4224 + 4096 + i * 8;
            Bp[0] = b_ss; Bp[1] = b_sv;
            Bp[2] = bvs[0]; Bp[3] = bvs[1]; Bp[4] = bvs[2];
            Bp[5] = bvv[0]; Bp[6] = bvv[1]; Bp[7] = bvv[2];
        }
    }
}

__global__ __launch_bounds__(512) void k_pre0(
        const float* __restrict__ z, const float* __restrict__ v,
        const float* __restrict__ w_s_in, const float* __restrict__ w_v_in,
        const float* __restrict__ W2, const float* __restrict__ b2,
        float* __restrict__ s, float* __restrict__ vec, float* __restrict__ A) {
    int node0 = blockIdx.x * 4;
    int tid = threadIdx.x;
    __shared__ float s_sh[4][16];
    __shared__ float vec_sh[4][48];
    if (tid < 256) {
        int k = tid >> 6, t = tid & 63;
        int node = node0 + k;
        if (t < 16) {
            float val = z[node] * w_s_in[t];
            s_sh[k][t] = val;
            s[node * 16 + t] = val;
        } else {
            int q = t - 16;
            int c = q / 3, d = q % 3;
            float val = v[node * 3 + d] * w_v_in[c];
            vec_sh[k][q] = val;
            vec[node * 48 + q] = val;
        }
    }
    __syncthreads();
    pre_phase2(node0, tid, s_sh, vec_sh, W2, b2, A);
}

__global__ __launch_bounds__(512) void k_pre_fused(
        const float* __restrict__ aggs, const float* __restrict__ aggv,
        const float* __restrict__ ws, const float* __restrict__ wv,
        const float* __restrict__ W2, const float* __restrict__ b2,
        float* __restrict__ s, float* __restrict__ vec, float* __restrict__ A) {
    int node0 = blockIdx.x * 4;
    int tid = threadIdx.x;
    __shared__ float s_sh[4][16];
    __shared__ float vec_sh[4][48];
    __shared__ float ash[4][16];
    __shared__ float avh[4][48];
    if (tid < 256) {
        int k = tid >> 6, t = tid & 63;
        int node = node0 + k;
        if (t < 16) {
            float a = 0.f;
#pragma unroll
            for (int p = 0; p < 8; ++p) a += aggs[p * 32768 + node * 16 + t];
            ash[k][t] = a;
        } else {
            int q = t - 16;
            float a = 0.f;
#pragma unroll
            for (int p = 0; p < 8; ++p) a += aggv[p * 98304 + node * 48 + q];
            avh[k][q] = a;
        }
    }
    __syncthreads();
    if (tid < 256) {
        int k = tid >> 6, t = tid & 63;
        int node = node0 + k;
        if (t < 16) {
            float acc = 0.f;
#pragma unroll
            for (int c = 0; c < 16; ++c) acc += ash[k][c] * ws[c * 16 + t];
            float val = s[node * 16 + t] + fmaxf(acc, 0.f);
            s_sh[k][t] = val;
            s[node * 16 + t] = val;
        } else {
            int q = t - 16, e = q / 3, d = q % 3;
            float acc = 0.f;
#pragma unroll
            for (int c = 0; c < 16; ++c) acc += avh[k][c * 3 + d] * wv[c * 16 + e];
            float val = vec[node * 48 + q] + acc;
            vec_sh[k][q] = val;
            vec[node * 48 + q] = val;
        }
    }
    __syncthreads();
    pre_phase2(node0, tid, s_sh, vec_sh, W2, b2, A);
}

__global__ __launch_bounds__(256) void k_edge(
        const float* __restrict__ pos, const float* __restrict__ A,
        const float* __restrict__ w1, const float* __restrict__ b1,
        float* __restrict__ aggs, float* __restrict__ aggv) {
    // grid 1024 = 32 batch * 4 dstgrp * 8 srcgrp; batch pinned to one XCD
    int blk = blockIdx.x;
    int xcd = blk & 7;
    int t = blk >> 3;                 // 0..127
    int b = xcd * 4 + (t >> 5);
    int rem = t & 31;
    int dgrp = rem >> 3;              // 0..3
    int sgrp = rem & 7;               // 0..7
    int w = threadIdx.x >> 6;
    int lane = threadIdx.x & 63;
    int dst0 = dgrp * 16 + w * 4;     // 4 dst per wave
    int i = lane & 15, hq = lane >> 4;

    __shared__ float pos_sh[NN * 3];
    if (threadIdx.x < NN * 3) pos_sh[threadIdx.x] = pos[(size_t)b * NN * 3 + threadIdx.x];
    __syncthreads();

    float w1r[8], b1r[8];
#pragma unroll
    for (int q = 0; q < 8; ++q) {
        w1r[q] = w1[hq * 8 + q];
        b1r[q] = b1[hq * 8 + q];
    }
    float pd[4][3];
#pragma unroll
    for (int k = 0; k < 4; ++k) {
        pd[k][0] = pos_sh[(dst0 + k) * 3 + 0];
        pd[k][1] = pos_sh[(dst0 + k) * 3 + 1];
        pd[k][2] = pos_sh[(dst0 + k) * 3 + 2];
    }

    float acc[4][4];
#pragma unroll
    for (int k = 0; k < 4; ++k)
#pragma unroll
        for (int c = 0; c < 4; ++c) acc[k][c] = 0.f;

    const float4* Abase = (const float4*)(A + (size_t)b * NN * 4224);

    for (int src = sgrp * 8; src < sgrp * 8 + 8; ++src) {
        const float4* Af = Abase + (size_t)src * 1056;
        float4 as0 = Af[0 * 64 + lane];
        float4 as1 = Af[1 * 64 + lane];
        float4 ax0 = Af[2 * 64 + lane];
        float4 ax1 = Af[3 * 64 + lane];
        float avsA[24], avvA[24];
#pragma unroll
        for (int q = 0; q < 6; ++q) {
            float4 tv = Af[(4 + q) * 64 + lane];
            avsA[q * 4 + 0] = tv.x; avsA[q * 4 + 1] = tv.y;
            avsA[q * 4 + 2] = tv.z; avsA[q * 4 + 3] = tv.w;
        }
#pragma unroll
        for (int q = 0; q < 6; ++q) {
            float4 tv = Af[(10 + q) * 64 + lane];
            avvA[q * 4 + 0] = tv.x; avvA[q * 4 + 1] = tv.y;
            avvA[q * 4 + 2] = tv.z; avvA[q * 4 + 3] = tv.w;
        }
        const float4* Bp4 = (const float4*)((const float*)Af + 4096) + i * 2;
        float4 bb0 = Bp4[0], bb1 = Bp4[1];

        float asl[8]  = {as0.x, as0.y, as0.z, as0.w, as1.x, as1.y, as1.z, as1.w};
        float asvl[8] = {ax0.x, ax0.y, ax0.z, ax0.w, ax1.x, ax1.y, ax1.z, ax1.w};

        float psx = pos_sh[src * 3 + 0];
        float psy = pos_sh[src * 3 + 1];
        float psz = pos_sh[src * 3 + 2];

#pragma unroll
        for (int k = 0; k < 4; ++k) {
            if (dst0 + k == src) continue;
            float dx = pd[k][0] - psx;
            float dy = pd[k][1] - psy;
            float dz = pd[k][2] - psz;
            float r = sqrtf(dx * dx + dy * dy + dz * dz);
            float inv = 1.f / (r + EPSV);
            float ux = dx * inv, uy = dy * inv, uz = dz * inv;

            float ms = 0.f, tt = 0.f;
            float a0 = 0.f, a1 = 0.f, a2 = 0.f;
            float v0 = 0.f, v1 = 0.f, v2 = 0.f;
#pragma unroll
            for (int hh = 0; hh < 8; ++hh) {
                float hv = r * w1r[hh] + b1r[hh];
                hv = hv > 0.f ? hv : 0.f;
                ms += hv * asl[hh];
                tt += hv * asvl[hh];
                a0 += hv * avsA[hh * 3 + 0];
                a1 += hv * avsA[hh * 3 + 1];
                a2 += hv * avsA[hh * 3 + 2];
                v0 += hv * avvA[hh * 3 + 0];
                v1 += hv * avvA[hh * 3 + 1];
                v2 += hv * avvA[hh * 3 + 2];
            }
            ms += ux * a0 + uy * a1 + uz * a2;
            if (hq == 0) {
                ms += bb0.x + ux * bb0.z + uy * bb0.w + uz * bb1.x;
                tt += bb0.y;
                v0 += bb1.y; v1 += bb1.z; v2 += bb1.w;
            }
            v0 += tt * ux; v1 += tt * uy; v2 += tt * uz;
            acc[k][0] += ms; acc[k][1] += v0; acc[k][2] += v1; acc[k][3] += v2;
        }
    }

#pragma unroll
    for (int k = 0; k < 4; ++k)
#pragma unroll
        for (int c = 0; c < 4; ++c) {
            acc[k][c] += __shfl_xor(acc[k][c], 16, 64);
            acc[k][c] += __shfl_xor(acc[k][c], 32, 64);
        }

    if (hq == 0) {
#pragma unroll
        for (int k = 0; k < 4; ++k) {
            int node = b * NN + dst0 + k;
            aggs[(size_t)sgrp * 32768 + node * 16 + i] = acc[k][0];
            float* vp = aggv + (size_t)sgrp * 98304 + node * 48 + i * 3;
            vp[0] = acc[k][1]; vp[1] = acc[k][2]; vp[2] = acc[k][3];
        }
    }
}

__global__ __launch_bounds__(256) void k_out(
        const float* __restrict__ aggv, const float* __restrict__ wv,
        const float* __restrict__ wvo, const float* __restrict__ vec,
        const float* __restrict__ pos, float* __restrict__ out) {
    int node0 = blockIdx.x * 4;
    int tid = threadIdx.x;
    int k = tid >> 6, t = tid & 63;
    int node = node0 + k;
    __shared__ float avh[4][48];
    __shared__ float vn[4][48];
    if (t < 48) {
        float a = 0.f;
#pragma unroll
        for (int p = 0; p < 8; ++p) a += aggv[p * 98304 + node * 48 + t];
        avh[k][t] = a;
    }
    __syncthreads();
    if (t < 48) {
        int e = t / 3, d = t % 3;
        float acc = 0.f;
#pragma unroll
        for (int c = 0; c < 16; ++c) acc += avh[k][c * 3 + d] * wv[c * 16 + e];
        vn[k][t] = (vec[node * 48 + t] + acc) * wvo[e];
    }
    __syncthreads();
    if (t < 3) {
        float acc = 0.f;
#pragma unroll
        for (int e = 0; e < 16; ++e) acc += vn[k][e * 3 + t];
        out[node * 3 + t] = acc + pos[node * 3 + t];
    }
}

extern "C" void kernel_launch(void* const* d_in, const int* in_sizes, int n_in,
                              void* d_out, int out_size, void* d_ws, size_t ws_size,
                              hipStream_t stream) {
    const float* pos = (const float*)d_in[0];
    const float* v   = (const float*)d_in[1];
    const float* z   = (const float*)d_in[2];
    const float* w_s_in = (const float*)d_in[3];
    const float* w_v_in = (const float*)d_in[4];
    const float* rw1 = (const float*)d_in[5];
    const float* rb1 = (const float*)d_in[6];
    const float* rw2 = (const float*)d_in[7];
    const float* rb2 = (const float*)d_in[8];
    const float* sws = (const float*)d_in[9];
    const float* swv = (const float*)d_in[10];
    const float* wvo = (const float*)d_in[11];
    float* out = (float*)d_out;

    float* wsf  = (float*)d_ws;
    float* s    = wsf + S_OFF;
    float* vec  = wsf + VEC_OFF;
    float* aggs = wsf + AGGS_OFF;
    float* aggv = wsf + AGGV_OFF;
    float* A    = wsf + A_OFF;

    k_pre0<<<512, 512, 0, stream>>>(z, v, w_s_in, w_v_in, rw2, rb2, s, vec, A);
    k_edge<<<1024, 256, 0, stream>>>(pos, A, rw1, rb1, aggs, aggv);

    k_pre_fused<<<512, 512, 0, stream>>>(aggs, aggv, sws, swv,
                                         rw2 + 32768, rb2 + 1024, s, vec, A);
    k_edge<<<1024, 256, 0, stream>>>(pos, A, rw1 + 32, rb1 + 32, aggs, aggv);

    k_pre_fused<<<512, 512, 0, stream>>>(aggs, aggv, sws + 256, swv + 256,
                                         rw2 + 65536, rb2 + 2048, s, vec, A);
    k_edge<<<1024, 256, 0, stream>>>(pos, A, rw1 + 64, rb1 + 64, aggs, aggv);

    k_out<<<512, 256, 0, stream>>>(aggv, swv + 512, wvo, vec, pos, out);
}

// Round 3
// 181.979 us; speedup vs baseline: 2.3019x; 1.5238x over previous
//
#include <hip/hip_runtime.h>

#define NF 16
#define HIDN 32
#define NB 32
#define NN 64
#define EPSV 1e-8f

typedef _Float16 f16x8 __attribute__((ext_vector_type(8)));
typedef float f32x4 __attribute__((ext_vector_type(4)));

// Workspace layout (float offsets):
//   slots : 0      (16)  -- 3 per-layer absmax uints
//   s     : 64     (32768)
//   vec   : 32832  (98304)
//   aggs  : 131136 (8*32768)
//   aggv  : 393280 (8*98304)
//   B2    : 1179712 (2048*128 fp32, sigma-scaled bias)
//   A2    : 1441856 (2048*4096 fp16, sigma-scaled)  total ~22.6 MB
// A2[node][f][h] fp16, f = i*8+cc; cc: 0=ss,1=sv,2..4=vs_d,5..7=vv_d
#define SLOT_OFF 0
#define S_OFF    64
#define VEC_OFF  32832
#define AGGS_OFF 131136
#define AGGV_OFF 393280
#define B2_OFF   1179712
#define A2_OFF   1441856

__device__ __forceinline__ void sigma_from_bits(unsigned mb, float* sig, float* invs) {
    int ex = (int)((mb >> 23) & 0xFF);
    if (ex == 0) { *sig = 1.f; *invs = 1.f; return; }
    *sig  = __uint_as_float((unsigned)(253 - ex) << 23);  // 2^(126-ex)
    *invs = __uint_as_float((unsigned)(ex + 1) << 23);    // 2^(ex-126)
}

__global__ __launch_bounds__(256) void k_init(
        const float* __restrict__ z, const float* __restrict__ v,
        const float* __restrict__ w_s_in, const float* __restrict__ w_v_in,
        float* __restrict__ s, float* __restrict__ vec, unsigned* __restrict__ slot0) {
    int idx = blockIdx.x * 256 + threadIdx.x;
    float val;
    if (idx < NB * NN * 16) {
        val = z[idx >> 4] * w_s_in[idx & 15];
        s[idx] = val;
    } else {
        int i2 = idx - NB * NN * 16;
        int node = i2 / 48, rem = i2 % 48;
        int ch = rem / 3, d = rem % 3;
        val = v[node * 3 + d] * w_v_in[ch];
        vec[i2] = val;
    }
    __shared__ float red[256];
    red[threadIdx.x] = fabsf(val);
    __syncthreads();
    for (int o = 128; o > 0; o >>= 1) {
        if (threadIdx.x < o) red[threadIdx.x] = fmaxf(red[threadIdx.x], red[threadIdx.x + o]);
        __syncthreads();
    }
    if (threadIdx.x == 0) atomicMax(slot0, __float_as_uint(red[0]));
}

__global__ __launch_bounds__(512) void k_pre(
        const float* __restrict__ s, const float* __restrict__ vec,
        const float* __restrict__ W2, const float* __restrict__ b2,
        const unsigned* __restrict__ slot,
        _Float16* __restrict__ A2, float* __restrict__ B2) {
    int node0 = blockIdx.x * 4;
    int tid = threadIdx.x;
    __shared__ float s_sh[4][16];
    __shared__ float vec_sh[4][48];
    if (tid < 256) {
        int k = tid >> 6, tt = tid & 63;
        int node = node0 + k;
        if (tt < 16) s_sh[k][tt] = s[node * 16 + tt];
        else vec_sh[k][tt - 16] = vec[node * 48 + tt - 16];
    }
    __syncthreads();

    float sigma, invs;
    sigma_from_bits(*slot, &sigma, &invs);

    int f = tid >> 2, hq8 = tid & 3;       // f 0..127, h-octet 0..3
    int i = f >> 3, cc = f & 7;
    int stream = (cc == 0) ? 0 : (cc == 1) ? 1 : (cc <= 4) ? 2 : 3;
    int d = (cc <= 1) ? 0 : (cc <= 4 ? cc - 2 : cc - 5);

    float ft[4][16];
#pragma unroll
    for (int k = 0; k < 4; ++k) {
        if (stream <= 1) {
#pragma unroll
            for (int q = 0; q < 4; ++q) {
                float4 x = *(const float4*)&s_sh[k][q * 4];
                ft[k][q * 4 + 0] = x.x; ft[k][q * 4 + 1] = x.y;
                ft[k][q * 4 + 2] = x.z; ft[k][q * 4 + 3] = x.w;
            }
        } else {
#pragma unroll
            for (int j = 0; j < 16; ++j) ft[k][j] = vec_sh[k][j * 3 + d];
        }
    }

    const float* wp = W2 + (size_t)(hq8 * 8) * 1024 + stream * 256 + i * 16;
    float out[4][8];
#pragma unroll
    for (int k = 0; k < 4; ++k)
#pragma unroll
        for (int h8 = 0; h8 < 8; ++h8) out[k][h8] = 0.f;

#pragma unroll
    for (int h8 = 0; h8 < 8; ++h8) {
        const float4* w4 = (const float4*)(wp + h8 * 1024);
        float4 a0 = w4[0], a1 = w4[1], a2 = w4[2], a3 = w4[3];
        float w[16] = {a0.x,a0.y,a0.z,a0.w, a1.x,a1.y,a1.z,a1.w,
                       a2.x,a2.y,a2.z,a2.w, a3.x,a3.y,a3.z,a3.w};
#pragma unroll
        for (int k = 0; k < 4; ++k) {
            float acc = 0.f;
#pragma unroll
            for (int j = 0; j < 16; ++j) acc += w[j] * ft[k][j];
            out[k][h8] = acc;
        }
    }

#pragma unroll
    for (int k = 0; k < 4; ++k) {
        f16x8 st;
#pragma unroll
        for (int h8 = 0; h8 < 8; ++h8) st[h8] = (_Float16)(out[k][h8] * sigma);
        *(f16x8*)(A2 + (size_t)(node0 + k) * 4096 + f * 32 + hq8 * 8) = st;
    }

    if (hq8 == 0) {
        const float* bp = b2 + stream * 256 + i * 16;
        float bw[16];
#pragma unroll
        for (int q = 0; q < 4; ++q) {
            float4 x = *(const float4*)(bp + q * 4);
            bw[q * 4 + 0] = x.x; bw[q * 4 + 1] = x.y; bw[q * 4 + 2] = x.z; bw[q * 4 + 3] = x.w;
        }
#pragma unroll
        for (int k = 0; k < 4; ++k) {
            float acc = 0.f;
#pragma unroll
            for (int j = 0; j < 16; ++j) acc += bw[j] * ft[k][j];
            B2[(size_t)(node0 + k) * 128 + f] = acc * sigma;
        }
    }
}

__global__ __launch_bounds__(256) void k_edge(
        const float* __restrict__ pos,
        const _Float16* __restrict__ A2, const float* __restrict__ B2,
        const float* __restrict__ w1, const float* __restrict__ b1,
        const unsigned* __restrict__ slot,
        float* __restrict__ aggs, float* __restrict__ aggv) {
    // grid 512 = 8 xcd * 4 b * 8 sgrp * 2 fhalf
    int blk = blockIdx.x;
    int xcd = blk & 7;
    int t = blk >> 3;                    // 0..63
    int b = xcd * 4 + (t >> 4);
    int rem = t & 15;
    int sgrp = rem >> 1, wfh = rem & 1;
    int wd = threadIdx.x >> 6;           // dst tile 0..3
    int lane = threadIdx.x & 63;
    int q = lane >> 4, col = lane & 15;
    int dst = wd * 16 + col;
    float qodd = (float)(q & 1);
    float o1 = qodd;                     // odd ? 1 : 0

    __shared__ float pos_sh[NN * 3];
    if (threadIdx.x < NN * 3) pos_sh[threadIdx.x] = pos[(size_t)b * NN * 3 + threadIdx.x];
    __syncthreads();

    float pdx = pos_sh[dst * 3 + 0], pdy = pos_sh[dst * 3 + 1], pdz = pos_sh[dst * 3 + 2];
    float w1r[8], b1r[8];
#pragma unroll
    for (int j = 0; j < 8; ++j) { w1r[j] = w1[q * 8 + j]; b1r[j] = b1[q * 8 + j]; }

    float sigma, invs;
    sigma_from_bits(*slot, &sigma, &invs);

    f32x4 acc[4][4];
#pragma unroll
    for (int mt = 0; mt < 4; ++mt)
#pragma unroll
        for (int u = 0; u < 4; ++u) acc[mt][u] = (f32x4){0.f, 0.f, 0.f, 0.f};
    float ms_p[4] = {0.f, 0.f, 0.f, 0.f};
    float mv_p[4][3];
#pragma unroll
    for (int mt = 0; mt < 4; ++mt) { mv_p[mt][0] = 0.f; mv_p[mt][1] = 0.f; mv_p[mt][2] = 0.f; }

    const _Float16* Ab = A2 + (size_t)b * NN * 4096 + (size_t)wfh * 2048 + col * 32 + q * 8;
    const float* Bb = B2 + (size_t)b * NN * 128 + wfh * 64 + q * 4;

    for (int src = sgrp * 8; src < sgrp * 8 + 8; ++src) {
        float psx = pos_sh[src * 3 + 0];
        float psy = pos_sh[src * 3 + 1];
        float psz = pos_sh[src * 3 + 2];
        float dx = pdx - psx, dy = pdy - psy, dz = pdz - psz;
        float r = sqrtf(dx * dx + dy * dy + dz * dz);
        float inv = 1.f / (r + EPSV);
        float ux = dx * inv, uy = dy * inv, uz = dz * inv;
        float vmask = (dst == src) ? 0.f : 1.f;

        f16x8 bf0, bf1, bf2, bf3;
#pragma unroll
        for (int j = 0; j < 8; ++j) {
            float hv = fmaxf(fmaf(r, w1r[j], b1r[j]), 0.f) * vmask;
            bf0[j] = (_Float16)hv;
            bf1[j] = (_Float16)(hv * ux);
            bf2[j] = (_Float16)(hv * uy);
            bf3[j] = (_Float16)(hv * uz);
        }

        const _Float16* Af = Ab + (size_t)src * 4096;
#pragma unroll
        for (int mt = 0; mt < 4; ++mt) {
            f16x8 af = *(const f16x8*)(Af + mt * 16 * 32);
            acc[mt][0] = __builtin_amdgcn_mfma_f32_16x16x32_f16(af, bf0, acc[mt][0], 0, 0, 0);
            acc[mt][1] = __builtin_amdgcn_mfma_f32_16x16x32_f16(af, bf1, acc[mt][1], 0, 0, 0);
            acc[mt][2] = __builtin_amdgcn_mfma_f32_16x16x32_f16(af, bf2, acc[mt][2], 0, 0, 0);
            acc[mt][3] = __builtin_amdgcn_mfma_f32_16x16x32_f16(af, bf3, acc[mt][3], 0, 0, 0);
        }

        // bias combine (B2 is sigma-scaled); selectors per src
        float s0  = qodd ? uz : 1.f;
        float zx  = qodd ? 0.f : ux;
        float zy  = qodd ? 0.f : uy;
        float exu = qodd ? 1.f : ux;
        float euy = qodd ? 0.f : uy;
        float euz = qodd ? 0.f : uz;
        const float* Bf = Bb + (size_t)src * 128;
#pragma unroll
        for (int mt = 0; mt < 4; ++mt) {
            float4 bv = *(const float4*)(Bf + mt * 16);
            float t0 = bv.x * vmask, t1 = bv.y * vmask, t2 = bv.z * vmask, t3 = bv.w * vmask;
            ms_p[mt]   += t0 * s0 + t2 * zx + t3 * zy;
            mv_p[mt][0] += t1 * exu;
            mv_p[mt][1] += t1 * euy + t2 * o1;
            mv_p[mt][2] += t1 * euz + t3 * o1;
        }
    }

    // fold MFMA accumulators per cc-rule
    if ((q & 1) == 0) {
#pragma unroll
        for (int mt = 0; mt < 4; ++mt) {
            ms_p[mt]    += acc[mt][0][0] + acc[mt][1][2] + acc[mt][2][3];
            mv_p[mt][0] += acc[mt][1][1];
            mv_p[mt][1] += acc[mt][2][1];
            mv_p[mt][2] += acc[mt][3][1];
        }
    } else {
#pragma unroll
        for (int mt = 0; mt < 4; ++mt) {
            ms_p[mt]    += acc[mt][3][0];
            mv_p[mt][0] += acc[mt][0][1];
            mv_p[mt][1] += acc[mt][0][2];
            mv_p[mt][2] += acc[mt][0][3];
        }
    }

#pragma unroll
    for (int mt = 0; mt < 4; ++mt) {
        ms_p[mt] = ms_p[mt] * invs + __shfl_xor(ms_p[mt] * invs, 16, 64);
        mv_p[mt][0] = mv_p[mt][0] * invs + __shfl_xor(mv_p[mt][0] * invs, 16, 64);
        mv_p[mt][1] = mv_p[mt][1] * invs + __shfl_xor(mv_p[mt][1] * invs, 16, 64);
        mv_p[mt][2] = mv_p[mt][2] * invs + __shfl_xor(mv_p[mt][2] * invs, 16, 64);
    }

    if ((q & 1) == 0) {
        int node = b * NN + dst;
#pragma unroll
        for (int mt = 0; mt < 4; ++mt) {
            int i = (wfh * 4 + mt) * 2 + (q >> 1);
            aggs[(size_t)sgrp * 32768 + node * 16 + i] = ms_p[mt];
            float* vp = aggv + (size_t)sgrp * 98304 + node * 48 + i * 3;
            vp[0] = mv_p[mt][0]; vp[1] = mv_p[mt][1]; vp[2] = mv_p[mt][2];
        }
    }
}

__global__ __launch_bounds__(256) void k_update(
        const float* __restrict__ aggs, const float* __restrict__ aggv,
        const float* __restrict__ ws, const float* __restrict__ wv,
        float* __restrict__ s, float* __restrict__ vec, unsigned* __restrict__ slotn) {
    int node0 = blockIdx.x * 4;
    int tid = threadIdx.x;
    int k = tid >> 6, tt = tid & 63;
    int node = node0 + k;
    __shared__ float ash[4][16];
    __shared__ float avh[4][48];
    if (tt < 16) {
        float a = 0.f;
#pragma unroll
        for (int p = 0; p < 8; ++p) a += aggs[(size_t)p * 32768 + node * 16 + tt];
        ash[k][tt] = a;
    } else {
        int qq = tt - 16;
        float a = 0.f;
#pragma unroll
        for (int p = 0; p < 8; ++p) a += aggv[(size_t)p * 98304 + node * 48 + qq];
        avh[k][qq] = a;
    }
    __syncthreads();
    float val;
    if (tt < 16) {
        float acc = 0.f;
#pragma unroll
        for (int c = 0; c < 16; ++c) acc += ash[k][c] * ws[c * 16 + tt];
        val = s[node * 16 + tt] + fmaxf(acc, 0.f);
        s[node * 16 + tt] = val;
    } else {
        int qq = tt - 16, e = qq / 3, d = qq % 3;
        float acc = 0.f;
#pragma unroll
        for (int c = 0; c < 16; ++c) acc += avh[k][c * 3 + d] * wv[c * 16 + e];
        val = vec[node * 48 + qq] + acc;
        vec[node * 48 + qq] = val;
    }
    __shared__ float red[256];
    red[tid] = fabsf(val);
    __syncthreads();
    for (int o = 128; o > 0; o >>= 1) {
        if (tid < o) red[tid] = fmaxf(red[tid], red[tid + o]);
        __syncthreads();
    }
    if (tid == 0) atomicMax(slotn, __float_as_uint(red[0]));
}

__global__ __launch_bounds__(256) void k_out(
        const float* __restrict__ aggv, const float* __restrict__ wv,
        const float* __restrict__ wvo, const float* __restrict__ vec,
        const float* __restrict__ pos, float* __restrict__ out) {
    int node0 = blockIdx.x * 4;
    int tid = threadIdx.x;
    int k = tid >> 6, t = tid & 63;
    int node = node0 + k;
    __shared__ float avh[4][48];
    __shared__ float vn[4][48];
    if (t < 48) {
        float a = 0.f;
#pragma unroll
        for (int p = 0; p < 8; ++p) a += aggv[(size_t)p * 98304 + node * 48 + t];
        avh[k][t] = a;
    }
    __syncthreads();
    if (t < 48) {
        int e = t / 3, d = t % 3;
        float acc = 0.f;
#pragma unroll
        for (int c = 0; c < 16; ++c) acc += avh[k][c * 3 + d] * wv[c * 16 + e];
        vn[k][t] = (vec[node * 48 + t] + acc) * wvo[e];
    }
    __syncthreads();
    if (t < 3) {
        float acc = 0.f;
#pragma unroll
        for (int e = 0; e < 16; ++e) acc += vn[k][e * 3 + t];
        out[node * 3 + t] = acc + pos[node * 3 + t];
    }
}

extern "C" void kernel_launch(void* const* d_in, const int* in_sizes, int n_in,
                              void* d_out, int out_size, void* d_ws, size_t ws_size,
                              hipStream_t stream) {
    const float* pos = (const float*)d_in[0];
    const float* v   = (const float*)d_in[1];
    const float* z   = (const float*)d_in[2];
    const float* w_s_in = (const float*)d_in[3];
    const float* w_v_in = (const float*)d_in[4];
    const float* rw1 = (const float*)d_in[5];
    const float* rb1 = (const float*)d_in[6];
    const float* rw2 = (const float*)d_in[7];
    const float* rb2 = (const float*)d_in[8];
    const float* sws = (const float*)d_in[9];
    const float* swv = (const float*)d_in[10];
    const float* wvo = (const float*)d_in[11];
    float* out = (float*)d_out;

    float* wsf  = (float*)d_ws;
    unsigned* slots = (unsigned*)(wsf + SLOT_OFF);
    float* s    = wsf + S_OFF;
    float* vec  = wsf + VEC_OFF;
    float* aggs = wsf + AGGS_OFF;
    float* aggv = wsf + AGGV_OFF;
    float* B2   = wsf + B2_OFF;
    _Float16* A2 = (_Float16*)(wsf + A2_OFF);

    hipMemsetAsync(slots, 0, 64, stream);
    k_init<<<512, 256, 0, stream>>>(z, v, w_s_in, w_v_in, s, vec, slots);
    for (int l = 0; l < 3; ++l) {
        k_pre<<<512, 512, 0, stream>>>(s, vec, rw2 + l * 32768, rb2 + l * 1024,
                                       slots + l, A2, B2);
        k_edge<<<512, 256, 0, stream>>>(pos, A2, B2, rw1 + l * 32, rb1 + l * 32,
                                        slots + l, aggs, aggv);
        if (l < 2)
            k_update<<<512, 256, 0, stream>>>(aggs, aggv, sws + l * 256, swv + l * 256,
                                              s, vec, slots + l + 1);
    }
    k_out<<<512, 256, 0, stream>>>(aggv, swv + 512, wvo, vec, pos, out);
}

// Round 4
// 160.236 us; speedup vs baseline: 2.6143x; 1.1357x over previous
//
#include <hip/hip_runtime.h>

#define NF 16
#define HIDN 32
#define NB 32
#define NN 64
#define EPSV 1e-8f

typedef _Float16 f16x8 __attribute__((ext_vector_type(8)));
typedef float f32x4 __attribute__((ext_vector_type(4)));

// Workspace layout (float offsets), all regions overwritten before read each call:
//   slotbits : 0    (16)   per-layer sigma source bits (written by k_pre, read by k_edge)
//   redzone  : 16   (512)  per-block absmax partials (written by k_update, read by k_pre)
//   s        : 576  (32768)
//   vec      : 33344 (98304)
//   aggs     : 131648 (8*32768)
//   aggv     : 393792 (8*98304)
//   B2       : 1180224 (2048*128 fp32, sigma-scaled bias)
//   A2       : 1442368 (2048*4096 fp16, sigma-scaled)
// A2[node][f][h] fp16, f = i*8+cc; cc: 0=ss,1=sv,2..4=vs_d,5..7=vv_d
#define SLOT_OFF 0
#define RED_OFF  16
#define S_OFF    576
#define VEC_OFF  33344
#define AGGS_OFF 131648
#define AGGV_OFF 393792
#define B2_OFF   1180224
#define A2_OFF   1442368

__device__ __forceinline__ void sigma_from_bits(unsigned mb, float* sig, float* invs) {
    int ex = (int)((mb >> 23) & 0xFF);
    if (ex == 0) { *sig = 1.f; *invs = 1.f; return; }
    *sig  = __uint_as_float((unsigned)(253 - ex) << 23);  // 2^(126-ex)
    *invs = __uint_as_float((unsigned)(ex + 1) << 23);    // 2^(ex-126)
}

template <int IS_L0>
__global__ __launch_bounds__(512) void k_pre(
        const float* __restrict__ z, const float* __restrict__ v,
        const float* __restrict__ w_s_in, const float* __restrict__ w_v_in,
        float* __restrict__ s, float* __restrict__ vec,
        const float* __restrict__ W2, const float* __restrict__ b2,
        const float* __restrict__ redzone, unsigned* __restrict__ slot_out,
        _Float16* __restrict__ A2, float* __restrict__ B2) {
    int node0 = blockIdx.x * 4;
    int tid = threadIdx.x;
    __shared__ float s_sh[4][16];
    __shared__ float vec_sh[4][48];
    __shared__ float red[512];

    float sigma, invs;
    if (IS_L0) {
        sigma = 1.f; invs = 1.f;
        if (tid == 0 && blockIdx.x == 0) *slot_out = __float_as_uint(0.5f);
        if (tid < 256) {
            int k = tid >> 6, tt = tid & 63;
            int node = node0 + k;
            if (tt < 16) {
                float val = z[node] * w_s_in[tt];
                s_sh[k][tt] = val;
                s[node * 16 + tt] = val;
            } else {
                int q = tt - 16, c = q / 3, d = q % 3;
                float val = v[node * 3 + d] * w_v_in[c];
                vec_sh[k][q] = val;
                vec[node * 48 + q] = val;
            }
        }
        __syncthreads();
    } else {
        red[tid] = redzone[tid];
        if (tid < 256) {
            int k = tid >> 6, tt = tid & 63;
            int node = node0 + k;
            if (tt < 16) s_sh[k][tt] = s[node * 16 + tt];
            else vec_sh[k][tt - 16] = vec[node * 48 + tt - 16];
        }
        __syncthreads();
#pragma unroll
        for (int o = 256; o > 0; o >>= 1) {
            if (tid < o) red[tid] = fmaxf(red[tid], red[tid + o]);
            __syncthreads();
        }
        unsigned mb = __float_as_uint(red[0]);
        sigma_from_bits(mb, &sigma, &invs);
        if (tid == 0) *slot_out = mb;
    }

    int f = tid >> 2, hq8 = tid & 3;       // f 0..127, h-octet 0..3
    int i = f >> 3, cc = f & 7;
    int stream = (cc == 0) ? 0 : (cc == 1) ? 1 : (cc <= 4) ? 2 : 3;
    int d = (cc <= 1) ? 0 : (cc <= 4 ? cc - 2 : cc - 5);

    float ft[4][16];
#pragma unroll
    for (int k = 0; k < 4; ++k) {
        if (stream <= 1) {
#pragma unroll
            for (int q = 0; q < 4; ++q) {
                float4 x = *(const float4*)&s_sh[k][q * 4];
                ft[k][q * 4 + 0] = x.x; ft[k][q * 4 + 1] = x.y;
                ft[k][q * 4 + 2] = x.z; ft[k][q * 4 + 3] = x.w;
            }
        } else {
#pragma unroll
            for (int j = 0; j < 16; ++j) ft[k][j] = vec_sh[k][j * 3 + d];
        }
    }

    const float* wp = W2 + (size_t)(hq8 * 8) * 1024 + stream * 256 + i * 16;
    float out[4][8];
#pragma unroll
    for (int k = 0; k < 4; ++k)
#pragma unroll
        for (int h8 = 0; h8 < 8; ++h8) out[k][h8] = 0.f;

#pragma unroll
    for (int h8 = 0; h8 < 8; ++h8) {
        const float4* w4 = (const float4*)(wp + h8 * 1024);
        float4 a0 = w4[0], a1 = w4[1], a2 = w4[2], a3 = w4[3];
        float w[16] = {a0.x,a0.y,a0.z,a0.w, a1.x,a1.y,a1.z,a1.w,
                       a2.x,a2.y,a2.z,a2.w, a3.x,a3.y,a3.z,a3.w};
#pragma unroll
        for (int k = 0; k < 4; ++k) {
            float acc = 0.f;
#pragma unroll
            for (int j = 0; j < 16; ++j) acc += w[j] * ft[k][j];
            out[k][h8] = acc;
        }
    }

#pragma unroll
    for (int k = 0; k < 4; ++k) {
        f16x8 st;
#pragma unroll
        for (int h8 = 0; h8 < 8; ++h8) st[h8] = (_Float16)(out[k][h8] * sigma);
        *(f16x8*)(A2 + (size_t)(node0 + k) * 4096 + f * 32 + hq8 * 8) = st;
    }

    if (hq8 == 0) {
        const float* bp = b2 + stream * 256 + i * 16;
        float bw[16];
#pragma unroll
        for (int q = 0; q < 4; ++q) {
            float4 x = *(const float4*)(bp + q * 4);
            bw[q * 4 + 0] = x.x; bw[q * 4 + 1] = x.y; bw[q * 4 + 2] = x.z; bw[q * 4 + 3] = x.w;
        }
#pragma unroll
        for (int k = 0; k < 4; ++k) {
            float acc = 0.f;
#pragma unroll
            for (int j = 0; j < 16; ++j) acc += bw[j] * ft[k][j];
            B2[(size_t)(node0 + k) * 128 + f] = acc * sigma;
        }
    }
}

__global__ __launch_bounds__(256) void k_edge(
        const float* __restrict__ pos,
        const _Float16* __restrict__ A2, const float* __restrict__ B2,
        const float* __restrict__ w1, const float* __restrict__ b1,
        const unsigned* __restrict__ slot,
        float* __restrict__ aggs, float* __restrict__ aggv) {
    // grid 512 = 8 xcd * 4 b * 8 sgrp * 2 fhalf
    int blk = blockIdx.x;
    int xcd = blk & 7;
    int t = blk >> 3;                    // 0..63
    int b = xcd * 4 + (t >> 4);
    int rem = t & 15;
    int sgrp = rem >> 1, wfh = rem & 1;
    int wd = threadIdx.x >> 6;           // dst tile 0..3
    int lane = threadIdx.x & 63;
    int q = lane >> 4, col = lane & 15;
    int dst = wd * 16 + col;
    float qodd = (float)(q & 1);
    float o1 = qodd;

    __shared__ float pos_sh[NN * 3];
    if (threadIdx.x < NN * 3) pos_sh[threadIdx.x] = pos[(size_t)b * NN * 3 + threadIdx.x];
    __syncthreads();

    float pdx = pos_sh[dst * 3 + 0], pdy = pos_sh[dst * 3 + 1], pdz = pos_sh[dst * 3 + 2];
    float w1r[8], b1r[8];
#pragma unroll
    for (int j = 0; j < 8; ++j) { w1r[j] = w1[q * 8 + j]; b1r[j] = b1[q * 8 + j]; }

    float sigma, invs;
    sigma_from_bits(*slot, &sigma, &invs);

    f32x4 acc[4][4];
#pragma unroll
    for (int mt = 0; mt < 4; ++mt)
#pragma unroll
        for (int u = 0; u < 4; ++u) acc[mt][u] = (f32x4){0.f, 0.f, 0.f, 0.f};
    float ms_p[4] = {0.f, 0.f, 0.f, 0.f};
    float mv_p[4][3];
#pragma unroll
    for (int mt = 0; mt < 4; ++mt) { mv_p[mt][0] = 0.f; mv_p[mt][1] = 0.f; mv_p[mt][2] = 0.f; }

    const _Float16* Ab = A2 + (size_t)b * NN * 4096 + (size_t)wfh * 2048 + col * 32 + q * 8;
    const float* Bb = B2 + (size_t)b * NN * 128 + wfh * 64 + q * 4;

    for (int src = sgrp * 8; src < sgrp * 8 + 8; ++src) {
        float psx = pos_sh[src * 3 + 0];
        float psy = pos_sh[src * 3 + 1];
        float psz = pos_sh[src * 3 + 2];
        float dx = pdx - psx, dy = pdy - psy, dz = pdz - psz;
        float r = sqrtf(dx * dx + dy * dy + dz * dz);
        float inv = 1.f / (r + EPSV);
        float ux = dx * inv, uy = dy * inv, uz = dz * inv;
        float vmask = (dst == src) ? 0.f : 1.f;

        f16x8 bf0, bf1, bf2, bf3;
#pragma unroll
        for (int j = 0; j < 8; ++j) {
            float hv = fmaxf(fmaf(r, w1r[j], b1r[j]), 0.f) * vmask;
            bf0[j] = (_Float16)hv;
            bf1[j] = (_Float16)(hv * ux);
            bf2[j] = (_Float16)(hv * uy);
            bf3[j] = (_Float16)(hv * uz);
        }

        const _Float16* Af = Ab + (size_t)src * 4096;
#pragma unroll
        for (int mt = 0; mt < 4; ++mt) {
            f16x8 af = *(const f16x8*)(Af + mt * 16 * 32);
            acc[mt][0] = __builtin_amdgcn_mfma_f32_16x16x32_f16(af, bf0, acc[mt][0], 0, 0, 0);
            acc[mt][1] = __builtin_amdgcn_mfma_f32_16x16x32_f16(af, bf1, acc[mt][1], 0, 0, 0);
            acc[mt][2] = __builtin_amdgcn_mfma_f32_16x16x32_f16(af, bf2, acc[mt][2], 0, 0, 0);
            acc[mt][3] = __builtin_amdgcn_mfma_f32_16x16x32_f16(af, bf3, acc[mt][3], 0, 0, 0);
        }

        float s0  = qodd ? uz : 1.f;
        float zx  = qodd ? 0.f : ux;
        float zy  = qodd ? 0.f : uy;
        float exu = qodd ? 1.f : ux;
        float euy = qodd ? 0.f : uy;
        float euz = qodd ? 0.f : uz;
        const float* Bf = Bb + (size_t)src * 128;
#pragma unroll
        for (int mt = 0; mt < 4; ++mt) {
            float4 bv = *(const float4*)(Bf + mt * 16);
            float t0 = bv.x * vmask, t1 = bv.y * vmask, t2 = bv.z * vmask, t3 = bv.w * vmask;
            ms_p[mt]   += t0 * s0 + t2 * zx + t3 * zy;
            mv_p[mt][0] += t1 * exu;
            mv_p[mt][1] += t1 * euy + t2 * o1;
            mv_p[mt][2] += t1 * euz + t3 * o1;
        }
    }

    if ((q & 1) == 0) {
#pragma unroll
        for (int mt = 0; mt < 4; ++mt) {
            ms_p[mt]    += acc[mt][0][0] + acc[mt][1][2] + acc[mt][2][3];
            mv_p[mt][0] += acc[mt][1][1];
            mv_p[mt][1] += acc[mt][2][1];
            mv_p[mt][2] += acc[mt][3][1];
        }
    } else {
#pragma unroll
        for (int mt = 0; mt < 4; ++mt) {
            ms_p[mt]    += acc[mt][3][0];
            mv_p[mt][0] += acc[mt][0][1];
            mv_p[mt][1] += acc[mt][0][2];
            mv_p[mt][2] += acc[mt][0][3];
        }
    }

#pragma unroll
    for (int mt = 0; mt < 4; ++mt) {
        ms_p[mt] = ms_p[mt] * invs + __shfl_xor(ms_p[mt] * invs, 16, 64);
        mv_p[mt][0] = mv_p[mt][0] * invs + __shfl_xor(mv_p[mt][0] * invs, 16, 64);
        mv_p[mt][1] = mv_p[mt][1] * invs + __shfl_xor(mv_p[mt][1] * invs, 16, 64);
        mv_p[mt][2] = mv_p[mt][2] * invs + __shfl_xor(mv_p[mt][2] * invs, 16, 64);
    }

    if ((q & 1) == 0) {
        int node = b * NN + dst;
#pragma unroll
        for (int mt = 0; mt < 4; ++mt) {
            int i = (wfh * 4 + mt) * 2 + (q >> 1);
            aggs[(size_t)sgrp * 32768 + node * 16 + i] = ms_p[mt];
            float* vp = aggv + (size_t)sgrp * 98304 + node * 48 + i * 3;
            vp[0] = mv_p[mt][0]; vp[1] = mv_p[mt][1]; vp[2] = mv_p[mt][2];
        }
    }
}

__global__ __launch_bounds__(256) void k_update(
        const float* __restrict__ aggs, const float* __restrict__ aggv,
        const float* __restrict__ ws, const float* __restrict__ wv,
        float* __restrict__ s, float* __restrict__ vec, float* __restrict__ redzone) {
    int node0 = blockIdx.x * 4;
    int tid = threadIdx.x;
    int k = tid >> 6, tt = tid & 63;
    int node = node0 + k;
    __shared__ float ash[4][16];
    __shared__ float avh[4][48];
    if (tt < 16) {
        float a = 0.f;
#pragma unroll
        for (int p = 0; p < 8; ++p) a += aggs[(size_t)p * 32768 + node * 16 + tt];
        ash[k][tt] = a;
    } else {
        int qq = tt - 16;
        float a = 0.f;
#pragma unroll
        for (int p = 0; p < 8; ++p) a += aggv[(size_t)p * 98304 + node * 48 + qq];
        avh[k][qq] = a;
    }
    __syncthreads();
    float val;
    if (tt < 16) {
        float acc = 0.f;
#pragma unroll
        for (int c = 0; c < 16; ++c) acc += ash[k][c] * ws[c * 16 + tt];
        val = s[node * 16 + tt] + fmaxf(acc, 0.f);
        s[node * 16 + tt] = val;
    } else {
        int qq = tt - 16, e = qq / 3, d = qq % 3;
        float acc = 0.f;
#pragma unroll
        for (int c = 0; c < 16; ++c) acc += avh[k][c * 3 + d] * wv[c * 16 + e];
        val = vec[node * 48 + qq] + acc;
        vec[node * 48 + qq] = val;
    }
    __shared__ float red[256];
    red[tid] = fabsf(val);
    __syncthreads();
#pragma unroll
    for (int o = 128; o > 0; o >>= 1) {
        if (tid < o) red[tid] = fmaxf(red[tid], red[tid + o]);
        __syncthreads();
    }
    if (tid == 0) redzone[blockIdx.x] = red[0];
}

__global__ __launch_bounds__(256) void k_out(
        const float* __restrict__ aggv, const float* __restrict__ wv,
        const float* __restrict__ wvo, const float* __restrict__ vec,
        const float* __restrict__ pos, float* __restrict__ out) {
    int node0 = blockIdx.x * 4;
    int tid = threadIdx.x;
    int k = tid >> 6, t = tid & 63;
    int node = node0 + k;
    __shared__ float avh[4][48];
    __shared__ float vn[4][48];
    if (t < 48) {
        float a = 0.f;
#pragma unroll
        for (int p = 0; p < 8; ++p) a += aggv[(size_t)p * 98304 + node * 48 + t];
        avh[k][t] = a;
    }
    __syncthreads();
    if (t < 48) {
        int e = t / 3, d = t % 3;
        float acc = 0.f;
#pragma unroll
        for (int c = 0; c < 16; ++c) acc += avh[k][c * 3 + d] * wv[c * 16 + e];
        vn[k][t] = (vec[node * 48 + t] + acc) * wvo[e];
    }
    __syncthreads();
    if (t < 3) {
        float acc = 0.f;
#pragma unroll
        for (int e = 0; e < 16; ++e) acc += vn[k][e * 3 + t];
        out[node * 3 + t] = acc + pos[node * 3 + t];
    }
}

extern "C" void kernel_launch(void* const* d_in, const int* in_sizes, int n_in,
                              void* d_out, int out_size, void* d_ws, size_t ws_size,
                              hipStream_t stream) {
    const float* pos = (const float*)d_in[0];
    const float* v   = (const float*)d_in[1];
    const float* z   = (const float*)d_in[2];
    const float* w_s_in = (const float*)d_in[3];
    const float* w_v_in = (const float*)d_in[4];
    const float* rw1 = (const float*)d_in[5];
    const float* rb1 = (const float*)d_in[6];
    const float* rw2 = (const float*)d_in[7];
    const float* rb2 = (const float*)d_in[8];
    const float* sws = (const float*)d_in[9];
    const float* swv = (const float*)d_in[10];
    const float* wvo = (const float*)d_in[11];
    float* out = (float*)d_out;

    float* wsf  = (float*)d_ws;
    unsigned* slotbits = (unsigned*)(wsf + SLOT_OFF);
    float* redzone = wsf + RED_OFF;
    float* s    = wsf + S_OFF;
    float* vec  = wsf + VEC_OFF;
    float* aggs = wsf + AGGS_OFF;
    float* aggv = wsf + AGGV_OFF;
    float* B2   = wsf + B2_OFF;
    _Float16* A2 = (_Float16*)(wsf + A2_OFF);

    k_pre<1><<<512, 512, 0, stream>>>(z, v, w_s_in, w_v_in, s, vec,
                                      rw2, rb2, redzone, slotbits, A2, B2);
    k_edge<<<512, 256, 0, stream>>>(pos, A2, B2, rw1, rb1, slotbits, aggs, aggv);

    k_update<<<512, 256, 0, stream>>>(aggs, aggv, sws, swv, s, vec, redzone);
    k_pre<0><<<512, 512, 0, stream>>>(z, v, w_s_in, w_v_in, s, vec,
                                      rw2 + 32768, rb2 + 1024, redzone, slotbits + 1, A2, B2);
    k_edge<<<512, 256, 0, stream>>>(pos, A2, B2, rw1 + 32, rb1 + 32, slotbits + 1, aggs, aggv);

    k_update<<<512, 256, 0, stream>>>(aggs, aggv, sws + 256, swv + 256, s, vec, redzone);
    k_pre<0><<<512, 512, 0, stream>>>(z, v, w_s_in, w_v_in, s, vec,
                                      rw2 + 65536, rb2 + 2048, redzone, slotbits + 2, A2, B2);
    k_edge<<<512, 256, 0, stream>>>(pos, A2, B2, rw1 + 64, rb1 + 64, slotbits + 2, aggs, aggv);

    k_out<<<512, 256, 0, stream>>>(aggv, swv + 512, wvo, vec, pos, out);
}